// Round 2
// baseline (1523.884 us; speedup 1.0000x reference)
//
#include <hip/hip_runtime.h>
#include <cstdint>
#include <cstddef>

// ---------------- constants ----------------
#define BATCH 8
#define NPTS 2048
#define KNN 20
#define M1 327680   // BATCH*NPTS*KNN
#define M2 16384    // BATCH*NPTS

typedef unsigned short ushort_t;

// ws layout (bytes) — peak-liveness packed, total 145,469,440 (~139 MiB)
#define OFF_XT    0UL          // 196608   float xt[b][n][3]
#define OFF_XX    196608UL     // 65536    float xx[b][n]
#define OFF_IDX   262144UL     // 1310720  int idx[b][n][20]
#define OFF_WT2   1572864UL    // 16384    float wT2[64][64]
#define OFF_WT3   1589248UL    // 32768    float wT3[64][128]
#define OFF_WT4   1622016UL    // 131072   float wT4[128][256]
#define OFF_WT5   1753088UL    // 1048576  float wT5[512][512]
#define OFF_STATS 2801664UL    // 40960    5 layers x (512 sum + 512 sumsq) double
#define OFF_SS    2842624UL    // 20480    5 layers x (512 scale + 512 shift) float
// REG0: y1 (41.9MB) -> y3 (83.9MB) -> y5 (16.8MB)
#define OFF_REG0  2863104UL    // 83886080
// REG1: y2 (41.9MB) -> rawmax(16.8MB)+rawmin(16.8MB)
#define OFF_REG1  86749184UL   // 41943040
#define OFF_XCAT  128692224UL  // 16777216 xcat[512][16384] bf16
#define WS_NEEDED 145469440UL

// ---------------- helpers ----------------
__device__ __forceinline__ float bf2f(unsigned short u) {
    union { unsigned int i; float f; } c; c.i = ((unsigned int)u) << 16; return c.f;
}
__device__ __forceinline__ unsigned short f2bf(float f) {
    union { float f; unsigned int i; } c; c.f = f;
    unsigned int x = c.i;
    unsigned int r = (x + 0x7fffu + ((x >> 16) & 1u)) >> 16;  // RNE
    return (unsigned short)r;
}
__device__ __forceinline__ void unpack8(uint4 u, float* v) {
    v[0] = bf2f((unsigned short)(u.x & 0xffffu)); v[1] = bf2f((unsigned short)(u.x >> 16));
    v[2] = bf2f((unsigned short)(u.y & 0xffffu)); v[3] = bf2f((unsigned short)(u.y >> 16));
    v[4] = bf2f((unsigned short)(u.z & 0xffffu)); v[5] = bf2f((unsigned short)(u.z >> 16));
    v[6] = bf2f((unsigned short)(u.w & 0xffffu)); v[7] = bf2f((unsigned short)(u.w >> 16));
}

// ---------------- prep: transpose x, compute xx ----------------
__global__ void prep_k(const float* __restrict__ x, float* __restrict__ xt, float* __restrict__ xx) {
    int t = blockIdx.x * 256 + threadIdx.x;   // 16384 = B*N
    int b = t >> 11, n = t & 2047;
    float v0 = x[((size_t)b * 3 + 0) * NPTS + n];
    float v1 = x[((size_t)b * 3 + 1) * NPTS + n];
    float v2 = x[((size_t)b * 3 + 2) * NPTS + n];
    xt[(size_t)t * 3 + 0] = v0; xt[(size_t)t * 3 + 1] = v1; xt[(size_t)t * 3 + 2] = v2;
    xx[t] = __fadd_rn(__fadd_rn(__fmul_rn(v0, v0), __fmul_rn(v1, v1)), __fmul_rn(v2, v2));
}

// ---------------- weight transpose w[o][c] -> wT[c][o] ----------------
__global__ void tr_k(const float* __restrict__ w, float* __restrict__ wT, int O, int C) {
    int t = blockIdx.x * 256 + threadIdx.x;
    if (t < O * C) {
        int o = t / C, c = t % C;
        wT[(size_t)c * O + o] = w[t];
    }
}

// ---------------- knn: top-20 neighbor indices per point ----------------
__launch_bounds__(256)
__global__ void knn_k(const float* __restrict__ xt, const float* __restrict__ xx, int* __restrict__ idx) {
    __shared__ float wv[4]; __shared__ int wi[4]; __shared__ int swin;
    int tid = threadIdx.x;
    int b = blockIdx.x >> 11, i = blockIdx.x & 2047;
    const float* xb  = xt + (size_t)b * NPTS * 3;
    const float* xxb = xx + (size_t)b * NPTS;
    float xi0 = xb[i * 3 + 0], xi1 = xb[i * 3 + 1], xi2 = xb[i * 3 + 2];
    float xxi = xxb[i];
    float v[8];
#pragma unroll
    for (int q = 0; q < 8; q++) {
        int j = tid + q * 256;
        float dot = __fadd_rn(__fadd_rn(__fmul_rn(xi0, xb[j * 3 + 0]),
                                        __fmul_rn(xi1, xb[j * 3 + 1])),
                              __fmul_rn(xi2, xb[j * 3 + 2]));
        v[q] = __fsub_rn(__fsub_rn(-xxi, __fmul_rn(-2.0f, dot)), xxb[j]);
    }
    int* out = idx + ((size_t)b * NPTS + i) * KNN;
    for (int t = 0; t < KNN; t++) {
        float bv = -3.0e38f; int bi = 0x7fffffff;
#pragma unroll
        for (int q = 0; q < 8; q++) {
            int j = tid + q * 256;
            if (v[q] > bv || (v[q] == bv && j < bi)) { bv = v[q]; bi = j; }
        }
#pragma unroll
        for (int off = 32; off; off >>= 1) {
            float ov = __shfl_down(bv, off);
            int   oi = __shfl_down(bi, off);
            if (ov > bv || (ov == bv && oi < bi)) { bv = ov; bi = oi; }
        }
        if ((tid & 63) == 0) { wv[tid >> 6] = bv; wi[tid >> 6] = bi; }
        __syncthreads();
        if (tid == 0) {
            float fv = wv[0]; int fi = wi[0];
            for (int w = 1; w < 4; w++)
                if (wv[w] > fv || (wv[w] == fv && wi[w] < fi)) { fv = wv[w]; fi = wi[w]; }
            out[t] = fi;
            swin = fi;
        }
        __syncthreads();
        int win = swin;
        if ((win & 255) == tid) v[win >> 8] = -3.4e38f;  // remove winner
    }
}

// ---------------- conv1: graph feature (6ch) x w1(64x6) -> y1[64][M1] bf16 ----------------
__launch_bounds__(256)
__global__ void conv1_k(const float* __restrict__ xt, const int* __restrict__ idx,
                        const float* __restrict__ w1, ushort_t* __restrict__ y1) {
    __shared__ float w[384];
    int tid = threadIdx.x;
    for (int t = tid; t < 384; t += 256) w[t] = w1[t];
    __syncthreads();
    int m = blockIdx.x * 256 + tid;        // < M1
    int b = m / (NPTS * KNN), r = m % (NPTS * KNN);
    int n = r / KNN, kk = r % KNN;
    int j = idx[((size_t)b * NPTS + n) * KNN + kk];
    const float* pi = xt + ((size_t)b * NPTS + n) * 3;
    const float* pj = xt + ((size_t)b * NPTS + j) * 3;
    float f0 = pj[0] - pi[0], f1 = pj[1] - pi[1], f2 = pj[2] - pi[2];
    float f3 = pi[0], f4 = pi[1], f5 = pi[2];
#pragma unroll
    for (int o = 0; o < 64; o++) {
        const float* wo = w + o * 6;
        float a = wo[0] * f0 + wo[1] * f1 + wo[2] * f2 + wo[3] * f3 + wo[4] * f4 + wo[5] * f5;
        y1[(size_t)o * M1 + m] = f2bf(a);
    }
}

// ---------------- generic tiled conv (layers 2,3,5): yout[o][m] = sum_c act(yin[c][m]) * wT[c][o]
template<int CIN, int COUT, int BO, bool BN>
__launch_bounds__(256, 2)
__global__ void conv_k(const ushort_t* __restrict__ yin, const float* __restrict__ wT,
                       const float* __restrict__ scale, const float* __restrict__ shift,
                       ushort_t* __restrict__ yout, int M) {
    __shared__ float hT[32][128];
    __shared__ float wS[32][BO];
    __shared__ float scl[BN ? CIN : 1];
    __shared__ float shf[BN ? CIN : 1];
    constexpr int NO = BO / 16;
    int tid = threadIdx.x;
    if constexpr (BN) {
        for (int c = tid; c < CIN; c += 256) { scl[c] = scale[c]; shf[c] = shift[c]; }
    }
    float acc[8][NO];
#pragma unroll
    for (int mi = 0; mi < 8; mi++)
#pragma unroll
        for (int oi = 0; oi < NO; oi++) acc[mi][oi] = 0.0f;
    int tx = tid & 15, ty = tid >> 4;
    int m0 = blockIdx.x * 128, o0 = blockIdx.y * BO;
    for (int kc = 0; kc < CIN; kc += 32) {
        __syncthreads();
#pragma unroll
        for (int ph = 0; ph < 2; ph++) {
            int rr = ty + ph * 16;
            int c = kc + rr;
            uint4 u = *(const uint4*)(yin + (size_t)c * M + m0 + tx * 8);
            float vv[8]; unpack8(u, vv);
            if constexpr (BN) {
                float s = scl[c], h = shf[c];
#pragma unroll
                for (int q = 0; q < 8; q++) vv[q] = fmaxf(fmaf(vv[q], s, h), 0.0f);
            }
            *(float4*)&hT[rr][tx * 8]     = make_float4(vv[0], vv[1], vv[2], vv[3]);
            *(float4*)&hT[rr][tx * 8 + 4] = make_float4(vv[4], vv[5], vv[6], vv[7]);
        }
#pragma unroll
        for (int pw = 0; pw < 2; pw++) {
            int rr = ty + pw * 16;
            const float4* src = (const float4*)(wT + (size_t)(kc + rr) * COUT + o0 + tx * NO);
            float4* dst = (float4*)&wS[rr][tx * NO];
#pragma unroll
            for (int q = 0; q < NO / 4; q++) dst[q] = src[q];
        }
        __syncthreads();
#pragma unroll
        for (int k = 0; k < 32; k++) {
            float a[8], bb[NO];
            *(float4*)&a[0] = *(const float4*)&hT[k][tx * 4];
            *(float4*)&a[4] = *(const float4*)&hT[k][tx * 4 + 64];
            *(float4*)&bb[0] = *(const float4*)&wS[k][ty * 4];
            if constexpr (BO == 128) *(float4*)&bb[4] = *(const float4*)&wS[k][ty * 4 + 64];
#pragma unroll
            for (int mi = 0; mi < 8; mi++)
#pragma unroll
                for (int oi = 0; oi < NO; oi++)
                    acc[mi][oi] = fmaf(a[mi], bb[oi], acc[mi][oi]);
        }
    }
#pragma unroll
    for (int oi = 0; oi < NO; oi++) {
        int o = o0 + ty * 4 + (oi & 3) + 64 * (oi >> 2);
#pragma unroll
        for (int g = 0; g < 2; g++) {
            ushort4 u;
            u.x = f2bf(acc[g * 4 + 0][oi]);
            u.y = f2bf(acc[g * 4 + 1][oi]);
            u.z = f2bf(acc[g * 4 + 2][oi]);
            u.w = f2bf(acc[g * 4 + 3][oi]);
            *(ushort4*)(yout + (size_t)o * M + m0 + tx * 4 + g * 64) = u;
        }
    }
}

// ---------------- conv4 fused: point-aligned BM=160 tile; epilogue reduces raw max/min
// over each k=20 window + per-channel sum/sumsq. y4 never materialized.
__launch_bounds__(256, 2)
__global__ void conv4_fused_k(const ushort_t* __restrict__ yin,   // y3 [128][M1] bf16
                              const float* __restrict__ wT,       // wT4 [128][256]
                              const float* __restrict__ scale,    // BN3 scale
                              const float* __restrict__ shift,
                              float* __restrict__ rawmax,         // [256][16384]
                              float* __restrict__ rawmin,
                              double* __restrict__ sum, double* __restrict__ sumsq) {
    __shared__ float hT[32][164];
    __shared__ float wS[32][128];
    __shared__ float scl[128], shf[128];
    __shared__ float red[8][165];
    __shared__ float psum[8][8], psumsq[8][8];
    int tid = threadIdx.x;
    int tx = tid & 31, ty = tid >> 5;           // tx: m-lane (32), ty: o-lane (8)
    int m0 = blockIdx.x * 160;                  // 2048 tiles
    int o0 = blockIdx.y * 128;                  // 2 tiles
    for (int c = tid; c < 128; c += 256) { scl[c] = scale[c]; shf[c] = shift[c]; }
    float acc[5][16];
#pragma unroll
    for (int j = 0; j < 5; j++)
#pragma unroll
        for (int i = 0; i < 16; i++) acc[j][i] = 0.0f;
    for (int kc = 0; kc < 128; kc += 32) {
        __syncthreads();
        // stage h: 32 c-rows x 160 m-cols (BN+ReLU applied), 640 x 8-wide loads
        for (int t = tid; t < 640; t += 256) {
            int row = t / 20, colg = t - row * 20;
            int c = kc + row;
            uint4 u = *(const uint4*)(yin + (size_t)c * M1 + m0 + colg * 8);
            float vv[8]; unpack8(u, vv);
            float s = scl[c], h = shf[c];
#pragma unroll
            for (int q = 0; q < 8; q++) vv[q] = fmaxf(fmaf(vv[q], s, h), 0.0f);
            *(float4*)&hT[row][colg * 8]     = make_float4(vv[0], vv[1], vv[2], vv[3]);
            *(float4*)&hT[row][colg * 8 + 4] = make_float4(vv[4], vv[5], vv[6], vv[7]);
        }
        // stage w: 32 c-rows x 128 o-cols
        for (int t = tid; t < 1024; t += 256) {
            int row = t >> 5, colg = t & 31;
            *(float4*)&wS[row][colg * 4] = *(const float4*)(wT + (size_t)(kc + row) * 256 + o0 + colg * 4);
        }
        __syncthreads();
#pragma unroll
        for (int k = 0; k < 32; k++) {
            float a[5], bb[16];
#pragma unroll
            for (int j = 0; j < 5; j++) a[j] = hT[k][tx + 32 * j];
#pragma unroll
            for (int q = 0; q < 4; q++) *(float4*)&bb[q * 4] = *(const float4*)&wS[k][ty * 16 + q * 4];
#pragma unroll
            for (int j = 0; j < 5; j++)
#pragma unroll
                for (int i = 0; i < 16; i++)
                    acc[j][i] = fmaf(a[j], bb[i], acc[j][i]);
        }
    }
    // epilogue: per channel slice, reduce k-windows + stats
    int pbase = m0 / KNN;   // 8 points per tile
    for (int oi = 0; oi < 16; oi++) {
        __syncthreads();
#pragma unroll
        for (int j = 0; j < 5; j++) red[ty][tx + 32 * j] = acc[j][oi];
        __syncthreads();
        if (tid < 64) {
            int oy = tid >> 3, p = tid & 7;
            const float* r = &red[oy][p * KNN];
            float mx = r[0], mn = r[0], sm = 0.0f, ss = 0.0f;
#pragma unroll
            for (int q = 0; q < KNN; q++) {
                float v = r[q];
                mx = fmaxf(mx, v); mn = fminf(mn, v);
                sm += v; ss = fmaf(v, v, ss);
            }
            int o = o0 + oy * 16 + oi;
            rawmax[(size_t)o * M2 + pbase + p] = mx;
            rawmin[(size_t)o * M2 + pbase + p] = mn;
            psum[oy][p] = sm; psumsq[oy][p] = ss;
        }
        __syncthreads();
        if (tid < 8) {
            float sm = 0.0f, ss = 0.0f;
#pragma unroll
            for (int p = 0; p < 8; p++) { sm += psum[tid][p]; ss += psumsq[tid][p]; }
            int o = o0 + tid * 16 + oi;
            atomicAdd(&sum[o], (double)sm);
            atomicAdd(&sumsq[o], (double)ss);
        }
    }
}

// ---------------- pool4 finalize: BN(monotone affine) of raw max/min + ReLU -> xcat ----------------
__launch_bounds__(256)
__global__ void pool4_k(const float* __restrict__ rawmax, const float* __restrict__ rawmin,
                        const float* __restrict__ scale, const float* __restrict__ shift,
                        ushort_t* __restrict__ xcat) {
    int o = blockIdx.x;                         // 256
    int p = blockIdx.y * 256 + threadIdx.x;     // 16384
    float s = scale[o], h = shift[o];
    float raw = (s >= 0.0f) ? rawmax[(size_t)o * M2 + p] : rawmin[(size_t)o * M2 + p];
    float v = fmaxf(fmaf(raw, s, h), 0.0f);
    xcat[(size_t)(256 + o) * M2 + p] = f2bf(v);
}

// ---------------- per-channel sum/sumsq over y[c][m] (bf16) ----------------
__launch_bounds__(256)
__global__ void stats_k(const ushort_t* __restrict__ y, double* __restrict__ sum,
                        double* __restrict__ sumsq, int M, int CHUNK) {
    __shared__ float ls[4], lss[4];
    int tid = threadIdx.x;
    int c = blockIdx.x;
    size_t base = (size_t)c * M + (size_t)blockIdx.y * CHUNK;
    float s = 0.f, ss = 0.f;
    for (int i = tid * 8; i < CHUNK; i += 2048) {
        uint4 u = *(const uint4*)(y + base + i);
        float vv[8]; unpack8(u, vv);
#pragma unroll
        for (int q = 0; q < 8; q++) { s += vv[q]; ss = fmaf(vv[q], vv[q], ss); }
    }
#pragma unroll
    for (int off = 32; off; off >>= 1) { s += __shfl_down(s, off); ss += __shfl_down(ss, off); }
    if ((tid & 63) == 0) { ls[tid >> 6] = s; lss[tid >> 6] = ss; }
    __syncthreads();
    if (tid == 0) {
        float ts = ls[0] + ls[1] + ls[2] + ls[3];
        float tss = lss[0] + lss[1] + lss[2] + lss[3];
        atomicAdd(&sum[c], (double)ts);
        atomicAdd(&sumsq[c], (double)tss);
    }
}

// ---------------- finalize BN: scale = g*rsqrt(var+eps), shift = b - mean*scale ----------------
__global__ void fin_k(const double* __restrict__ sum, const double* __restrict__ sumsq,
                      const float* __restrict__ g, const float* __restrict__ bb,
                      float* __restrict__ scale, float* __restrict__ shift, int C, double invcnt) {
    int c = blockIdx.x * blockDim.x + threadIdx.x;
    if (c < C) {
        double m = sum[c] * invcnt;
        double v = sumsq[c] * invcnt - m * m;
        if (v < 0.0) v = 0.0;
        float sc = g[c] / sqrtf((float)v + 1e-5f);
        scale[c] = sc;
        shift[c] = bb[c] - (float)m * sc;
    }
}

// ---------------- maxpool over k (with BN+ReLU) -> xcat bf16 (layers 1-3) ----------------
__launch_bounds__(256)
__global__ void maxpool_k(const ushort_t* __restrict__ y, const float* __restrict__ scale,
                          const float* __restrict__ shift, ushort_t* __restrict__ xcat,
                          int coff, int M) {
    int c = blockIdx.x;
    int p = blockIdx.y * 256 + threadIdx.x;   // < 16384
    float sc = scale[c], sh = shift[c];
    size_t base = (size_t)c * M + (size_t)p * KNN;
    float mx = 0.0f;   // relu floor
#pragma unroll
    for (int q = 0; q < KNN; q++) {
        float vv = fmaf(bf2f(y[base + q]), sc, sh);
        mx = fmaxf(mx, vv);
    }
    xcat[(size_t)(coff + c) * M2 + p] = f2bf(mx);
}

// ---------------- output: BN5+ReLU, layout [b][c][n] fp32 ----------------
__launch_bounds__(256)
__global__ void out_k(const ushort_t* __restrict__ y5, const float* __restrict__ scale,
                      const float* __restrict__ shift, float* __restrict__ out) {
    int c = blockIdx.x;
    int p = blockIdx.y * 256 + threadIdx.x;   // < 16384
    float vv = fmaxf(fmaf(bf2f(y5[(size_t)c * M2 + p]), scale[c], shift[c]), 0.0f);
    int b = p >> 11, n = p & 2047;
    out[((size_t)b * 512 + c) * NPTS + n] = vv;
}

// ---------------- host ----------------
extern "C" void kernel_launch(void* const* d_in, const int* in_sizes, int n_in,
                              void* d_out, int out_size, void* d_ws, size_t ws_size,
                              hipStream_t stream) {
    (void)in_sizes; (void)n_in; (void)out_size;
    if (ws_size < WS_NEEDED) return;  // fail cleanly (absmax mismatch) instead of faulting
    const float* x  = (const float*)d_in[0];
    const float* w1 = (const float*)d_in[1];
    const float* g1 = (const float*)d_in[2];
    const float* b1 = (const float*)d_in[3];
    const float* w2 = (const float*)d_in[4];
    const float* g2 = (const float*)d_in[5];
    const float* b2 = (const float*)d_in[6];
    const float* w3 = (const float*)d_in[7];
    const float* g3 = (const float*)d_in[8];
    const float* b3 = (const float*)d_in[9];
    const float* w4 = (const float*)d_in[10];
    const float* g4 = (const float*)d_in[11];
    const float* b4 = (const float*)d_in[12];
    const float* w5 = (const float*)d_in[13];
    const float* g5 = (const float*)d_in[14];
    const float* b5 = (const float*)d_in[15];

    char* ws = (char*)d_ws;
    float* xt  = (float*)(ws + OFF_XT);
    float* xx  = (float*)(ws + OFF_XX);
    int*   idx = (int*)(ws + OFF_IDX);
    float* wT2 = (float*)(ws + OFF_WT2);
    float* wT3 = (float*)(ws + OFF_WT3);
    float* wT4 = (float*)(ws + OFF_WT4);
    float* wT5 = (float*)(ws + OFF_WT5);
    ushort_t* y1 = (ushort_t*)(ws + OFF_REG0);             // 41.9MB
    ushort_t* y2 = (ushort_t*)(ws + OFF_REG1);             // 41.9MB
    ushort_t* y3 = (ushort_t*)(ws + OFF_REG0);             // 83.9MB (y1 dead)
    float* rawmax = (float*)(ws + OFF_REG1);               // 16.8MB (y2 dead)
    float* rawmin = (float*)(ws + OFF_REG1 + 16777216UL);  // 16.8MB
    ushort_t* y5 = (ushort_t*)(ws + OFF_REG0);             // 16.8MB (y3 dead)
    ushort_t* xcat = (ushort_t*)(ws + OFF_XCAT);           // 16.8MB

    double* sum[5]; double* sumsq[5]; float* scl[5]; float* shf[5];
    for (int l = 0; l < 5; l++) {
        sum[l]   = (double*)(ws + OFF_STATS + (size_t)l * 8192);
        sumsq[l] = sum[l] + 512;
        scl[l]   = (float*)(ws + OFF_SS + (size_t)l * 4096);
        shf[l]   = scl[l] + 512;
    }

    hipMemsetAsync(ws + OFF_STATS, 0, 40960, stream);
    prep_k<<<64, 256, 0, stream>>>(x, xt, xx);
    tr_k<<<16,   256, 0, stream>>>(w2, wT2, 64, 64);
    tr_k<<<32,   256, 0, stream>>>(w3, wT3, 128, 64);
    tr_k<<<128,  256, 0, stream>>>(w4, wT4, 256, 128);
    tr_k<<<1024, 256, 0, stream>>>(w5, wT5, 512, 512);
    knn_k<<<16384, 256, 0, stream>>>(xt, xx, idx);

    // layer 1: graph feature -> conv1
    conv1_k<<<1280, 256, 0, stream>>>(xt, idx, w1, y1);
    stats_k<<<dim3(64, 16), 256, 0, stream>>>(y1, sum[0], sumsq[0], M1, 20480);
    fin_k<<<1, 512, 0, stream>>>(sum[0], sumsq[0], g1, b1, scl[0], shf[0], 64, 1.0 / 327680.0);
    maxpool_k<<<dim3(64, 64), 256, 0, stream>>>(y1, scl[0], shf[0], xcat, 0, M1);

    // layer 2: 64 -> 64
    conv_k<64, 64, 64, true><<<dim3(2560, 1), 256, 0, stream>>>(y1, wT2, scl[0], shf[0], y2, M1);
    stats_k<<<dim3(64, 16), 256, 0, stream>>>(y2, sum[1], sumsq[1], M1, 20480);
    fin_k<<<1, 512, 0, stream>>>(sum[1], sumsq[1], g2, b2, scl[1], shf[1], 64, 1.0 / 327680.0);
    maxpool_k<<<dim3(64, 64), 256, 0, stream>>>(y2, scl[1], shf[1], xcat, 64, M1);

    // layer 3: 64 -> 128
    conv_k<64, 128, 128, true><<<dim3(2560, 1), 256, 0, stream>>>(y2, wT3, scl[1], shf[1], y3, M1);
    stats_k<<<dim3(128, 16), 256, 0, stream>>>(y3, sum[2], sumsq[2], M1, 20480);
    fin_k<<<1, 512, 0, stream>>>(sum[2], sumsq[2], g3, b3, scl[2], shf[2], 128, 1.0 / 327680.0);
    maxpool_k<<<dim3(128, 64), 256, 0, stream>>>(y3, scl[2], shf[2], xcat, 128, M1);

    // layer 4: 128 -> 256, fused stats + k-window raw max/min (no y4 buffer)
    conv4_fused_k<<<dim3(2048, 2), 256, 0, stream>>>(y3, wT4, scl[2], shf[2],
                                                     rawmax, rawmin, sum[3], sumsq[3]);
    fin_k<<<1, 512, 0, stream>>>(sum[3], sumsq[3], g4, b4, scl[3], shf[3], 256, 1.0 / 327680.0);
    pool4_k<<<dim3(256, 64), 256, 0, stream>>>(rawmax, rawmin, scl[3], shf[3], xcat);

    // layer 5: 512 -> 512 on pooled features (input already activated -> no BN on load)
    conv_k<512, 512, 128, false><<<dim3(128, 4), 256, 0, stream>>>(xcat, wT5, nullptr, nullptr, y5, M2);
    stats_k<<<dim3(512, 1), 256, 0, stream>>>(y5, sum[4], sumsq[4], M2, 16384);
    fin_k<<<1, 512, 0, stream>>>(sum[4], sumsq[4], g5, b5, scl[4], shf[4], 512, 1.0 / 16384.0);
    out_k<<<dim3(512, 64), 256, 0, stream>>>(y5, scl[4], shf[4], (float*)d_out);
}

// Round 3
// 1494.882 us; speedup vs baseline: 1.0194x; 1.0194x over previous
//
#include <hip/hip_runtime.h>
#include <cstdint>
#include <cstddef>

// ---------------- constants ----------------
#define BATCH 8
#define NPTS 2048
#define KNN 20
#define M1 327680   // BATCH*NPTS*KNN
#define M2 16384    // BATCH*NPTS

typedef unsigned short ushort_t;

// ws layout (bytes) — peak-liveness packed, total 145,469,440 (~139 MiB)
#define OFF_XT    0UL          // 196608   float xt[b][n][3]
#define OFF_XX    196608UL     // 65536    float xx[b][n]
#define OFF_IDX   262144UL     // 1310720  int idx[b][n][20]
#define OFF_WT2   1572864UL    // 16384    float wT2[64][64]
#define OFF_WT3   1589248UL    // 32768    float wT3[64][128]
#define OFF_WT4   1622016UL    // 131072   float wT4[128][256]
#define OFF_WT5   1753088UL    // 1048576  float wT5[512][512]
#define OFF_STATS 2801664UL    // 40960    5 layers x (512 sum + 512 sumsq) double
#define OFF_SS    2842624UL    // 20480    5 layers x (512 scale + 512 shift) float
// REG0: y1 (41.9MB) -> y3 (83.9MB) -> y5 (16.8MB)
#define OFF_REG0  2863104UL    // 83886080
// REG1: y2 (41.9MB) -> rawmax(16.8MB)+rawmin(16.8MB)
#define OFF_REG1  86749184UL   // 41943040
#define OFF_XCAT  128692224UL  // 16777216 xcat[512][16384] bf16
#define WS_NEEDED 145469440UL

// ---------------- helpers ----------------
__device__ __forceinline__ float bf2f(unsigned short u) {
    union { unsigned int i; float f; } c; c.i = ((unsigned int)u) << 16; return c.f;
}
__device__ __forceinline__ unsigned short f2bf(float f) {
    union { float f; unsigned int i; } c; c.f = f;
    unsigned int x = c.i;
    unsigned int r = (x + 0x7fffu + ((x >> 16) & 1u)) >> 16;  // RNE
    return (unsigned short)r;
}
__device__ __forceinline__ void unpack8(uint4 u, float* v) {
    v[0] = bf2f((unsigned short)(u.x & 0xffffu)); v[1] = bf2f((unsigned short)(u.x >> 16));
    v[2] = bf2f((unsigned short)(u.y & 0xffffu)); v[3] = bf2f((unsigned short)(u.y >> 16));
    v[4] = bf2f((unsigned short)(u.z & 0xffffu)); v[5] = bf2f((unsigned short)(u.z >> 16));
    v[6] = bf2f((unsigned short)(u.w & 0xffffu)); v[7] = bf2f((unsigned short)(u.w >> 16));
}

// ---------------- prep: transpose x, compute xx ----------------
__global__ void prep_k(const float* __restrict__ x, float* __restrict__ xt, float* __restrict__ xx) {
    int t = blockIdx.x * 256 + threadIdx.x;   // 16384 = B*N
    int b = t >> 11, n = t & 2047;
    float v0 = x[((size_t)b * 3 + 0) * NPTS + n];
    float v1 = x[((size_t)b * 3 + 1) * NPTS + n];
    float v2 = x[((size_t)b * 3 + 2) * NPTS + n];
    xt[(size_t)t * 3 + 0] = v0; xt[(size_t)t * 3 + 1] = v1; xt[(size_t)t * 3 + 2] = v2;
    xx[t] = __fadd_rn(__fadd_rn(__fmul_rn(v0, v0), __fmul_rn(v1, v1)), __fmul_rn(v2, v2));
}

// ---------------- weight transpose w[o][c] -> wT[c][o] ----------------
__global__ void tr_k(const float* __restrict__ w, float* __restrict__ wT, int O, int C) {
    int t = blockIdx.x * 256 + threadIdx.x;
    if (t < O * C) {
        int o = t / C, c = t % C;
        wT[(size_t)c * O + o] = w[t];
    }
}

// ---------------- knn: wave-per-point top-20 (no LDS, no syncthreads) ----------------
__launch_bounds__(256)
__global__ void knn_k(const float* __restrict__ xt, const float* __restrict__ xx, int* __restrict__ idx) {
    int tid = threadIdx.x;
    int l = tid & 63;
    int pid = blockIdx.x * 4 + (tid >> 6);    // 16384 points, 4 waves/block
    int b = pid >> 11, i = pid & 2047;
    const float* xb  = xt + (size_t)b * NPTS * 3;
    const float* xxb = xx + (size_t)b * NPTS;
    float xi0 = xb[i * 3 + 0], xi1 = xb[i * 3 + 1], xi2 = xb[i * 3 + 2];
    float xxi = xxb[i];
    float v[32];
#pragma unroll
    for (int q = 0; q < 32; q++) {
        int j = l + q * 64;
        float dot = __fadd_rn(__fadd_rn(__fmul_rn(xi0, xb[j * 3 + 0]),
                                        __fmul_rn(xi1, xb[j * 3 + 1])),
                              __fmul_rn(xi2, xb[j * 3 + 2]));
        // dist = (-xx_i - (-2*dot)) - xx_j  (numpy order)
        v[q] = __fsub_rn(__fsub_rn(-xxi, __fmul_rn(-2.0f, dot)), xxb[j]);
    }
    int* out = idx + (size_t)pid * KNN;
    for (int t = 0; t < KNN; t++) {
        // local argmax over this lane's 32 values (ascending j -> lowest index on tie)
        float bv = -3.0e38f; int bi = 0x7fffffff;
#pragma unroll
        for (int q = 0; q < 32; q++) {
            int j = l + q * 64;
            if (v[q] > bv) { bv = v[q]; bi = j; }
        }
        // butterfly argmax across 64 lanes, tie-break lower index
#pragma unroll
        for (int off = 1; off < 64; off <<= 1) {
            float ov = __shfl_xor(bv, off);
            int   oi = __shfl_xor(bi, off);
            if (ov > bv || (ov == bv && oi < bi)) { bv = ov; bi = oi; }
        }
        if (l == 0) out[t] = bi;
        // invalidate winner (static register indexing only)
        int owner = bi & 63, qw = bi >> 6;
        bool isown = (l == owner);
#pragma unroll
        for (int q = 0; q < 32; q++)
            if (isown && q == qw) v[q] = -3.4e38f;
    }
}

// ---------------- conv1: graph feature (6ch) x w1(64x6) -> y1[64][M1] bf16 ----------------
__launch_bounds__(256)
__global__ void conv1_k(const float* __restrict__ xt, const int* __restrict__ idx,
                        const float* __restrict__ w1, ushort_t* __restrict__ y1) {
    __shared__ float w[384];
    int tid = threadIdx.x;
    for (int t = tid; t < 384; t += 256) w[t] = w1[t];
    __syncthreads();
    int m = blockIdx.x * 256 + tid;        // < M1
    int b = m / (NPTS * KNN), r = m % (NPTS * KNN);
    int n = r / KNN, kk = r % KNN;
    int j = idx[((size_t)b * NPTS + n) * KNN + kk];
    const float* pi = xt + ((size_t)b * NPTS + n) * 3;
    const float* pj = xt + ((size_t)b * NPTS + j) * 3;
    float f0 = pj[0] - pi[0], f1 = pj[1] - pi[1], f2 = pj[2] - pi[2];
    float f3 = pi[0], f4 = pi[1], f5 = pi[2];
#pragma unroll
    for (int o = 0; o < 64; o++) {
        const float* wo = w + o * 6;
        float a = wo[0] * f0 + wo[1] * f1 + wo[2] * f2 + wo[3] * f3 + wo[4] * f4 + wo[5] * f5;
        y1[(size_t)o * M1 + m] = f2bf(a);
    }
}

// ---------------- generic tiled conv (layers 2,3,5): yout[o][m] = sum_c act(yin[c][m]) * wT[c][o]
template<int CIN, int COUT, int BO, bool BN>
__launch_bounds__(256, 2)
__global__ void conv_k(const ushort_t* __restrict__ yin, const float* __restrict__ wT,
                       const float* __restrict__ scale, const float* __restrict__ shift,
                       ushort_t* __restrict__ yout, int M) {
    __shared__ float hT[32][128];
    __shared__ float wS[32][BO];
    __shared__ float scl[BN ? CIN : 1];
    __shared__ float shf[BN ? CIN : 1];
    constexpr int NO = BO / 16;
    int tid = threadIdx.x;
    if constexpr (BN) {
        for (int c = tid; c < CIN; c += 256) { scl[c] = scale[c]; shf[c] = shift[c]; }
    }
    float acc[8][NO];
#pragma unroll
    for (int mi = 0; mi < 8; mi++)
#pragma unroll
        for (int oi = 0; oi < NO; oi++) acc[mi][oi] = 0.0f;
    int tx = tid & 15, ty = tid >> 4;
    int m0 = blockIdx.x * 128, o0 = blockIdx.y * BO;
    for (int kc = 0; kc < CIN; kc += 32) {
        __syncthreads();
#pragma unroll
        for (int ph = 0; ph < 2; ph++) {
            int rr = ty + ph * 16;
            int c = kc + rr;
            uint4 u = *(const uint4*)(yin + (size_t)c * M + m0 + tx * 8);
            float vv[8]; unpack8(u, vv);
            if constexpr (BN) {
                float s = scl[c], h = shf[c];
#pragma unroll
                for (int q = 0; q < 8; q++) vv[q] = fmaxf(fmaf(vv[q], s, h), 0.0f);
            }
            *(float4*)&hT[rr][tx * 8]     = make_float4(vv[0], vv[1], vv[2], vv[3]);
            *(float4*)&hT[rr][tx * 8 + 4] = make_float4(vv[4], vv[5], vv[6], vv[7]);
        }
#pragma unroll
        for (int pw = 0; pw < 2; pw++) {
            int rr = ty + pw * 16;
            const float4* src = (const float4*)(wT + (size_t)(kc + rr) * COUT + o0 + tx * NO);
            float4* dst = (float4*)&wS[rr][tx * NO];
#pragma unroll
            for (int q = 0; q < NO / 4; q++) dst[q] = src[q];
        }
        __syncthreads();
#pragma unroll
        for (int k = 0; k < 32; k++) {
            float a[8], bb[NO];
            *(float4*)&a[0] = *(const float4*)&hT[k][tx * 4];
            *(float4*)&a[4] = *(const float4*)&hT[k][tx * 4 + 64];
            *(float4*)&bb[0] = *(const float4*)&wS[k][ty * 4];
            if constexpr (BO == 128) *(float4*)&bb[4] = *(const float4*)&wS[k][ty * 4 + 64];
#pragma unroll
            for (int mi = 0; mi < 8; mi++)
#pragma unroll
                for (int oi = 0; oi < NO; oi++)
                    acc[mi][oi] = fmaf(a[mi], bb[oi], acc[mi][oi]);
        }
    }
#pragma unroll
    for (int oi = 0; oi < NO; oi++) {
        int o = o0 + ty * 4 + (oi & 3) + 64 * (oi >> 2);
#pragma unroll
        for (int g = 0; g < 2; g++) {
            ushort4 u;
            u.x = f2bf(acc[g * 4 + 0][oi]);
            u.y = f2bf(acc[g * 4 + 1][oi]);
            u.z = f2bf(acc[g * 4 + 2][oi]);
            u.w = f2bf(acc[g * 4 + 3][oi]);
            *(ushort4*)(yout + (size_t)o * M + m0 + tx * 4 + g * 64) = u;
        }
    }
}

// ---------------- conv4 fused: BM=160 (8 points), BO=64, no spill.
// Epilogue reduces raw max/min over each k=20 window + per-channel sum/sumsq.
__launch_bounds__(256, 2)
__global__ void conv4_fused_k(const ushort_t* __restrict__ yin,   // y3 [128][M1] bf16
                              const float* __restrict__ wT,       // wT4 [128][256]
                              const float* __restrict__ scale,    // BN3 scale
                              const float* __restrict__ shift,
                              float* __restrict__ rawmax,         // [256][16384]
                              float* __restrict__ rawmin,
                              double* __restrict__ sum, double* __restrict__ sumsq) {
    __shared__ float hT[32][164];
    __shared__ float wS[32][64];
    __shared__ float scl[128], shf[128];
    __shared__ float red[8][165];
    int tid = threadIdx.x;
    int tx = tid & 31, ty = tid >> 5;           // tx: m-lane (32), ty: o-lane (8)
    int m0 = blockIdx.x * 160;                  // 2048 tiles
    int o0 = blockIdx.y * 64;                   // 4 tiles
    for (int c = tid; c < 128; c += 256) { scl[c] = scale[c]; shf[c] = shift[c]; }
    float acc[5][8];
#pragma unroll
    for (int j = 0; j < 5; j++)
#pragma unroll
        for (int i = 0; i < 8; i++) acc[j][i] = 0.0f;
    for (int kc = 0; kc < 128; kc += 32) {
        __syncthreads();
        // stage h: 32 c-rows x 160 m-cols (BN+ReLU applied)
        for (int t = tid; t < 640; t += 256) {
            int row = t / 20, colg = t - row * 20;
            int c = kc + row;
            uint4 u = *(const uint4*)(yin + (size_t)c * M1 + m0 + colg * 8);
            float vv[8]; unpack8(u, vv);
            float s = scl[c], h = shf[c];
#pragma unroll
            for (int q = 0; q < 8; q++) vv[q] = fmaxf(fmaf(vv[q], s, h), 0.0f);
            *(float4*)&hT[row][colg * 8]     = make_float4(vv[0], vv[1], vv[2], vv[3]);
            *(float4*)&hT[row][colg * 8 + 4] = make_float4(vv[4], vv[5], vv[6], vv[7]);
        }
        // stage w: 32 c-rows x 64 o-cols
        for (int t = tid; t < 512; t += 256) {
            int row = t >> 4, col = (t & 15) * 4;
            *(float4*)&wS[row][col] = *(const float4*)(wT + (size_t)(kc + row) * 256 + o0 + col);
        }
        __syncthreads();
#pragma unroll
        for (int k = 0; k < 32; k++) {
            float a[5], bb[8];
#pragma unroll
            for (int j = 0; j < 5; j++) a[j] = hT[k][tx + 32 * j];
            *(float4*)&bb[0] = *(const float4*)&wS[k][ty * 8];
            *(float4*)&bb[4] = *(const float4*)&wS[k][ty * 8 + 4];
#pragma unroll
            for (int j = 0; j < 5; j++)
#pragma unroll
                for (int i = 0; i < 8; i++)
                    acc[j][i] = fmaf(a[j], bb[i], acc[j][i]);
        }
    }
    // epilogue: per output-channel slice, transpose via LDS, reduce k-windows + stats
    int pbase = blockIdx.x * 8;                 // 8 points per tile
#pragma unroll
    for (int i = 0; i < 8; i++) {
        __syncthreads();
#pragma unroll
        for (int j = 0; j < 5; j++) red[ty][tx + 32 * j] = acc[j][i];
        __syncthreads();
        if (tid < 64) {
            int oy = tid >> 3, p = tid & 7;
            const float* r = &red[oy][p * KNN];
            float mx = r[0], mn = r[0], sm = 0.0f, ss = 0.0f;
#pragma unroll
            for (int q = 0; q < KNN; q++) {
                float vv = r[q];
                mx = fmaxf(mx, vv); mn = fminf(mn, vv);
                sm += vv; ss = fmaf(vv, vv, ss);
            }
            int o = o0 + oy * 8 + i;
            rawmax[(size_t)o * M2 + pbase + p] = mx;
            rawmin[(size_t)o * M2 + pbase + p] = mn;
            // 8-lane shuffle reduce for stats (lanes oy*8+p)
#pragma unroll
            for (int off = 4; off; off >>= 1) {
                sm += __shfl_down(sm, off);
                ss += __shfl_down(ss, off);
            }
            if (p == 0) {
                atomicAdd(&sum[o], (double)sm);
                atomicAdd(&sumsq[o], (double)ss);
            }
        }
    }
}

// ---------------- pool4 finalize: BN(monotone affine) of raw max/min + ReLU -> xcat ----------------
__launch_bounds__(256)
__global__ void pool4_k(const float* __restrict__ rawmax, const float* __restrict__ rawmin,
                        const float* __restrict__ scale, const float* __restrict__ shift,
                        ushort_t* __restrict__ xcat) {
    int o = blockIdx.x;                         // 256
    int p = blockIdx.y * 256 + threadIdx.x;     // 16384
    float s = scale[o], h = shift[o];
    float raw = (s >= 0.0f) ? rawmax[(size_t)o * M2 + p] : rawmin[(size_t)o * M2 + p];
    float v = fmaxf(fmaf(raw, s, h), 0.0f);
    xcat[(size_t)(256 + o) * M2 + p] = f2bf(v);
}

// ---------------- per-channel sum/sumsq over y[c][m] (bf16) ----------------
__launch_bounds__(256)
__global__ void stats_k(const ushort_t* __restrict__ y, double* __restrict__ sum,
                        double* __restrict__ sumsq, int M, int CHUNK) {
    __shared__ float ls[4], lss[4];
    int tid = threadIdx.x;
    int c = blockIdx.x;
    size_t base = (size_t)c * M + (size_t)blockIdx.y * CHUNK;
    float s = 0.f, ss = 0.f;
    for (int i = tid * 8; i < CHUNK; i += 2048) {
        uint4 u = *(const uint4*)(y + base + i);
        float vv[8]; unpack8(u, vv);
#pragma unroll
        for (int q = 0; q < 8; q++) { s += vv[q]; ss = fmaf(vv[q], vv[q], ss); }
    }
#pragma unroll
    for (int off = 32; off; off >>= 1) { s += __shfl_down(s, off); ss += __shfl_down(ss, off); }
    if ((tid & 63) == 0) { ls[tid >> 6] = s; lss[tid >> 6] = ss; }
    __syncthreads();
    if (tid == 0) {
        float ts = ls[0] + ls[1] + ls[2] + ls[3];
        float tss = lss[0] + lss[1] + lss[2] + lss[3];
        atomicAdd(&sum[c], (double)ts);
        atomicAdd(&sumsq[c], (double)tss);
    }
}

// ---------------- finalize BN: scale = g*rsqrt(var+eps), shift = b - mean*scale ----------------
__global__ void fin_k(const double* __restrict__ sum, const double* __restrict__ sumsq,
                      const float* __restrict__ g, const float* __restrict__ bb,
                      float* __restrict__ scale, float* __restrict__ shift, int C, double invcnt) {
    int c = blockIdx.x * blockDim.x + threadIdx.x;
    if (c < C) {
        double m = sum[c] * invcnt;
        double v = sumsq[c] * invcnt - m * m;
        if (v < 0.0) v = 0.0;
        float sc = g[c] / sqrtf((float)v + 1e-5f);
        scale[c] = sc;
        shift[c] = bb[c] - (float)m * sc;
    }
}

// ---------------- maxpool over k (with BN+ReLU) -> xcat bf16 (layers 1-3) ----------------
__launch_bounds__(256)
__global__ void maxpool_k(const ushort_t* __restrict__ y, const float* __restrict__ scale,
                          const float* __restrict__ shift, ushort_t* __restrict__ xcat,
                          int coff, int M) {
    int c = blockIdx.x;
    int p = blockIdx.y * 256 + threadIdx.x;   // < 16384
    float sc = scale[c], sh = shift[c];
    size_t base = (size_t)c * M + (size_t)p * KNN;
    float mx = 0.0f;   // relu floor
#pragma unroll
    for (int q = 0; q < KNN; q++) {
        float vv = fmaf(bf2f(y[base + q]), sc, sh);
        mx = fmaxf(mx, vv);
    }
    xcat[(size_t)(coff + c) * M2 + p] = f2bf(mx);
}

// ---------------- output: BN5+ReLU, layout [b][c][n] fp32 ----------------
__launch_bounds__(256)
__global__ void out_k(const ushort_t* __restrict__ y5, const float* __restrict__ scale,
                      const float* __restrict__ shift, float* __restrict__ out) {
    int c = blockIdx.x;
    int p = blockIdx.y * 256 + threadIdx.x;   // < 16384
    float vv = fmaxf(fmaf(bf2f(y5[(size_t)c * M2 + p]), scale[c], shift[c]), 0.0f);
    int b = p >> 11, n = p & 2047;
    out[((size_t)b * 512 + c) * NPTS + n] = vv;
}

// ---------------- host ----------------
extern "C" void kernel_launch(void* const* d_in, const int* in_sizes, int n_in,
                              void* d_out, int out_size, void* d_ws, size_t ws_size,
                              hipStream_t stream) {
    (void)in_sizes; (void)n_in; (void)out_size;
    if (ws_size < WS_NEEDED) return;  // fail cleanly instead of faulting
    const float* x  = (const float*)d_in[0];
    const float* w1 = (const float*)d_in[1];
    const float* g1 = (const float*)d_in[2];
    const float* b1 = (const float*)d_in[3];
    const float* w2 = (const float*)d_in[4];
    const float* g2 = (const float*)d_in[5];
    const float* b2 = (const float*)d_in[6];
    const float* w3 = (const float*)d_in[7];
    const float* g3 = (const float*)d_in[8];
    const float* b3 = (const float*)d_in[9];
    const float* w4 = (const float*)d_in[10];
    const float* g4 = (const float*)d_in[11];
    const float* b4 = (const float*)d_in[12];
    const float* w5 = (const float*)d_in[13];
    const float* g5 = (const float*)d_in[14];
    const float* b5 = (const float*)d_in[15];

    char* ws = (char*)d_ws;
    float* xt  = (float*)(ws + OFF_XT);
    float* xx  = (float*)(ws + OFF_XX);
    int*   idx = (int*)(ws + OFF_IDX);
    float* wT2 = (float*)(ws + OFF_WT2);
    float* wT3 = (float*)(ws + OFF_WT3);
    float* wT4 = (float*)(ws + OFF_WT4);
    float* wT5 = (float*)(ws + OFF_WT5);
    ushort_t* y1 = (ushort_t*)(ws + OFF_REG0);             // 41.9MB
    ushort_t* y2 = (ushort_t*)(ws + OFF_REG1);             // 41.9MB
    ushort_t* y3 = (ushort_t*)(ws + OFF_REG0);             // 83.9MB (y1 dead)
    float* rawmax = (float*)(ws + OFF_REG1);               // 16.8MB (y2 dead)
    float* rawmin = (float*)(ws + OFF_REG1 + 16777216UL);  // 16.8MB
    ushort_t* y5 = (ushort_t*)(ws + OFF_REG0);             // 16.8MB (y3 dead)
    ushort_t* xcat = (ushort_t*)(ws + OFF_XCAT);           // 16.8MB

    double* sum[5]; double* sumsq[5]; float* scl[5]; float* shf[5];
    for (int l = 0; l < 5; l++) {
        sum[l]   = (double*)(ws + OFF_STATS + (size_t)l * 8192);
        sumsq[l] = sum[l] + 512;
        scl[l]   = (float*)(ws + OFF_SS + (size_t)l * 4096);
        shf[l]   = scl[l] + 512;
    }

    hipMemsetAsync(ws + OFF_STATS, 0, 40960, stream);
    prep_k<<<64, 256, 0, stream>>>(x, xt, xx);
    tr_k<<<16,   256, 0, stream>>>(w2, wT2, 64, 64);
    tr_k<<<32,   256, 0, stream>>>(w3, wT3, 128, 64);
    tr_k<<<128,  256, 0, stream>>>(w4, wT4, 256, 128);
    tr_k<<<1024, 256, 0, stream>>>(w5, wT5, 512, 512);
    knn_k<<<4096, 256, 0, stream>>>(xt, xx, idx);

    // layer 1: graph feature -> conv1
    conv1_k<<<1280, 256, 0, stream>>>(xt, idx, w1, y1);
    stats_k<<<dim3(64, 16), 256, 0, stream>>>(y1, sum[0], sumsq[0], M1, 20480);
    fin_k<<<1, 512, 0, stream>>>(sum[0], sumsq[0], g1, b1, scl[0], shf[0], 64, 1.0 / 327680.0);
    maxpool_k<<<dim3(64, 64), 256, 0, stream>>>(y1, scl[0], shf[0], xcat, 0, M1);

    // layer 2: 64 -> 64
    conv_k<64, 64, 64, true><<<dim3(2560, 1), 256, 0, stream>>>(y1, wT2, scl[0], shf[0], y2, M1);
    stats_k<<<dim3(64, 16), 256, 0, stream>>>(y2, sum[1], sumsq[1], M1, 20480);
    fin_k<<<1, 512, 0, stream>>>(sum[1], sumsq[1], g2, b2, scl[1], shf[1], 64, 1.0 / 327680.0);
    maxpool_k<<<dim3(64, 64), 256, 0, stream>>>(y2, scl[1], shf[1], xcat, 64, M1);

    // layer 3: 64 -> 128 (BO=64, two o-tiles: keep VGPRs low)
    conv_k<64, 128, 64, true><<<dim3(2560, 2), 256, 0, stream>>>(y2, wT3, scl[1], shf[1], y3, M1);
    stats_k<<<dim3(128, 16), 256, 0, stream>>>(y3, sum[2], sumsq[2], M1, 20480);
    fin_k<<<1, 512, 0, stream>>>(sum[2], sumsq[2], g3, b3, scl[2], shf[2], 128, 1.0 / 327680.0);
    maxpool_k<<<dim3(128, 64), 256, 0, stream>>>(y3, scl[2], shf[2], xcat, 128, M1);

    // layer 4: 128 -> 256, fused stats + k-window raw max/min (no y4 buffer)
    conv4_fused_k<<<dim3(2048, 4), 256, 0, stream>>>(y3, wT4, scl[2], shf[2],
                                                     rawmax, rawmin, sum[3], sumsq[3]);
    fin_k<<<1, 512, 0, stream>>>(sum[3], sumsq[3], g4, b4, scl[3], shf[3], 256, 1.0 / 327680.0);
    pool4_k<<<dim3(256, 64), 256, 0, stream>>>(rawmax, rawmin, scl[3], shf[3], xcat);

    // layer 5: 512 -> 512 on pooled features (BO=64, 8 o-tiles)
    conv_k<512, 512, 64, false><<<dim3(128, 8), 256, 0, stream>>>(xcat, wT5, nullptr, nullptr, y5, M2);
    stats_k<<<dim3(512, 1), 256, 0, stream>>>(y5, sum[4], sumsq[4], M2, 16384);
    fin_k<<<1, 512, 0, stream>>>(sum[4], sumsq[4], g5, b5, scl[4], shf[4], 512, 1.0 / 16384.0);
    out_k<<<dim3(512, 64), 256, 0, stream>>>(y5, scl[4], shf[4], (float*)d_out);
}

// Round 5
// 924.677 us; speedup vs baseline: 1.6480x; 1.6167x over previous
//
#include <hip/hip_runtime.h>
#include <cstdint>
#include <cstddef>

// ---------------- constants ----------------
#define BATCH 8
#define NPTS 2048
#define KNN 20
#define M1 327680   // BATCH*NPTS*KNN
#define M2 16384    // BATCH*NPTS

typedef unsigned short ushort_t;
typedef __attribute__((ext_vector_type(8))) short bf16x8;   // 8 bf16 = 4 VGPRs
typedef __attribute__((ext_vector_type(4))) float f32x4;    // MFMA acc

// ws layout (bytes) — total 145,469,440
#define OFF_XT    0UL          // 196608   float xt[b*n][3]
#define OFF_XX    196608UL     // 65536    float xx[b*n]
#define OFF_IDX   262144UL     // 1310720  int idx[b*n][20]
#define OFF_WH2   1572864UL    // 8192   bf16 [64][64]
#define OFF_WL2   1581056UL    // 8192
#define OFF_WH3   1589248UL    // 16384  bf16 [128][64]
#define OFF_WL3   1605632UL    // 16384
#define OFF_WH4   1622016UL    // 65536  bf16 [256][128]
#define OFF_WL4   1687552UL    // 65536
#define OFF_WH5   1753088UL    // 524288 bf16 [512][512]
#define OFF_WL5   2277376UL    // 524288
#define OFF_STATS 2801664UL    // 40960   5 x (512 sum + 512 sumsq) double
#define OFF_SS    2842624UL    // 20480   5 x (512 scale + 512 shift) float
// REG0: y1 [M1][64] (41.9MB) -> y3 [M1][128] (83.9MB) -> y5 [M2][512] (16.8MB)
#define OFF_REG0  2863104UL    // 83886080
// REG1: y2 [M1][64] (41.9MB) -> rawmax+rawmin [M2][256] f32 (33.5MB) + sp4 (2MB)
#define OFF_REG1  86749184UL   // 41943040
#define OFF_XCAT  128692224UL  // 16777216 xcat[M2][512] bf16
#define WS_NEEDED 145469440UL

// ---------------- helpers ----------------
__device__ __forceinline__ float bf2f(unsigned short u) {
    union { unsigned int i; float f; } c; c.i = ((unsigned int)u) << 16; return c.f;
}
__device__ __forceinline__ unsigned short f2bf(float f) {
    union { float f; unsigned int i; } c; c.f = f;
    unsigned int x = c.i;
    unsigned int r = (x + 0x7fffu + ((x >> 16) & 1u)) >> 16;  // RNE
    return (unsigned short)r;
}
__device__ __forceinline__ unsigned int pack2(float a, float b) {
    return (unsigned int)f2bf(a) | ((unsigned int)f2bf(b) << 16);
}
__device__ __forceinline__ void unpack8(uint4 u, float* v) {
    v[0] = bf2f((unsigned short)(u.x & 0xffffu)); v[1] = bf2f((unsigned short)(u.x >> 16));
    v[2] = bf2f((unsigned short)(u.y & 0xffffu)); v[3] = bf2f((unsigned short)(u.y >> 16));
    v[4] = bf2f((unsigned short)(u.z & 0xffffu)); v[5] = bf2f((unsigned short)(u.z >> 16));
    v[6] = bf2f((unsigned short)(u.w & 0xffffu)); v[7] = bf2f((unsigned short)(u.w >> 16));
}

// ---------------- prep: transpose x, compute xx ----------------
__global__ void prep_k(const float* __restrict__ x, float* __restrict__ xt, float* __restrict__ xx) {
    int t = blockIdx.x * 256 + threadIdx.x;   // 16384
    int b = t >> 11, n = t & 2047;
    float v0 = x[((size_t)b * 3 + 0) * NPTS + n];
    float v1 = x[((size_t)b * 3 + 1) * NPTS + n];
    float v2 = x[((size_t)b * 3 + 2) * NPTS + n];
    xt[(size_t)t * 3 + 0] = v0; xt[(size_t)t * 3 + 1] = v1; xt[(size_t)t * 3 + 2] = v2;
    xx[t] = __fadd_rn(__fadd_rn(__fmul_rn(v0, v0), __fmul_rn(v1, v1)), __fmul_rn(v2, v2));
}

// ---------------- weight split: fp32 -> bf16 hi + bf16 lo ----------------
__global__ void wsplit_k(const float* __restrict__ w, ushort_t* __restrict__ hi,
                         ushort_t* __restrict__ lo, int n) {
    int t = blockIdx.x * 256 + threadIdx.x;
    if (t < n) {
        float f = w[t];
        ushort_t h = f2bf(f);
        hi[t] = h;
        lo[t] = f2bf(f - bf2f(h));
    }
}

// ---------------- knn: wave-per-point top-20 ----------------
__launch_bounds__(256)
__global__ void knn_k(const float* __restrict__ xt, const float* __restrict__ xx, int* __restrict__ idx) {
    int tid = threadIdx.x;
    int l = tid & 63;
    int pid = blockIdx.x * 4 + (tid >> 6);
    int b = pid >> 11;
    const float* xb  = xt + (size_t)b * NPTS * 3;
    const float* xxb = xx + (size_t)b * NPTS;
    int i = pid & 2047;
    float xi0 = xb[i * 3 + 0], xi1 = xb[i * 3 + 1], xi2 = xb[i * 3 + 2];
    float xxi = xxb[i];
    float v[32];
#pragma unroll
    for (int q = 0; q < 32; q++) {
        int j = l + q * 64;
        float dot = __fadd_rn(__fadd_rn(__fmul_rn(xi0, xb[j * 3 + 0]),
                                        __fmul_rn(xi1, xb[j * 3 + 1])),
                              __fmul_rn(xi2, xb[j * 3 + 2]));
        v[q] = __fsub_rn(__fsub_rn(-xxi, __fmul_rn(-2.0f, dot)), xxb[j]);
    }
    int* out = idx + (size_t)pid * KNN;
    for (int t = 0; t < KNN; t++) {
        float bv = -3.0e38f; int bi = 0x7fffffff;
#pragma unroll
        for (int q = 0; q < 32; q++) {
            int j = l + q * 64;
            if (v[q] > bv) { bv = v[q]; bi = j; }
        }
#pragma unroll
        for (int off = 1; off < 64; off <<= 1) {
            float ov = __shfl_xor(bv, off);
            int   oi = __shfl_xor(bi, off);
            if (ov > bv || (ov == bv && oi < bi)) { bv = ov; bi = oi; }
        }
        if (l == 0) out[t] = bi;
        int owner = bi & 63, qw = bi >> 6;
        bool isown = (l == owner);
#pragma unroll
        for (int q = 0; q < 32; q++)
            if (isown && q == qw) v[q] = -3.4e38f;
    }
}

// ---------------- conv1: graph feature (6ch) x w1(64x6) -> y1 NHWC [m][64] bf16 ----------------
__launch_bounds__(256)
__global__ void conv1_k(const float* __restrict__ xt, const int* __restrict__ idx,
                        const float* __restrict__ w1, ushort_t* __restrict__ y1) {
    __shared__ float w[384];
    int tid = threadIdx.x;
    for (int t = tid; t < 384; t += 256) w[t] = w1[t];
    __syncthreads();
    int m = blockIdx.x * 256 + tid;        // < M1; idx flat index == m
    int nb = m / KNN;                      // b*N + n
    int b = nb >> 11;
    int j = idx[m];
    const float* pi = xt + (size_t)nb * 3;
    const float* pj = xt + ((size_t)(b * NPTS + j)) * 3;
    float f0 = pj[0] - pi[0], f1 = pj[1] - pi[1], f2 = pj[2] - pi[2];
    float f3 = pi[0], f4 = pi[1], f5 = pi[2];
#pragma unroll
    for (int o8 = 0; o8 < 8; o8++) {
        uint4 u;
        unsigned int* up = (unsigned int*)&u;
#pragma unroll
        for (int e2 = 0; e2 < 4; e2++) {
            const float* wa = w + (o8 * 8 + e2 * 2) * 6;
            const float* wb = wa + 6;
            float r0 = wa[0]*f0 + wa[1]*f1 + wa[2]*f2 + wa[3]*f3 + wa[4]*f4 + wa[5]*f5;
            float r1 = wb[0]*f0 + wb[1]*f1 + wb[2]*f2 + wb[3]*f3 + wb[4]*f4 + wb[5]*f5;
            up[e2] = pack2(r0, r1);
        }
        *(uint4*)(y1 + (size_t)m * 64 + o8 * 8) = u;
    }
}

// ---------------- generic MFMA conv (layers 2,3,5) ----------------
// yout[m][o] = sum_c act(yin[m][c]) * w[o][c], NHWC. Block: 128m x 64o, 4 waves (32m each).
template<int CIN, int COUT, bool BN>
__launch_bounds__(256)
__global__ void conv_mfma_k(const ushort_t* __restrict__ yin,
                            const ushort_t* __restrict__ whi,
                            const ushort_t* __restrict__ wlo,
                            const float* __restrict__ scale,
                            const float* __restrict__ shift,
                            ushort_t* __restrict__ yout) {
    constexpr int SMEM = 28672 + (BN ? CIN * 8 : 0);
    __shared__ char smem[SMEM];
    ushort_t* hA = (ushort_t*)smem;             // [128][56] bf16 (rows 112B, 16B aligned)
    ushort_t* wH = (ushort_t*)(smem + 14336);   // [64][56]
    ushort_t* wL = (ushort_t*)(smem + 21504);   // [64][56]
    float* scl = (float*)(smem + 28672);
    float* shf = scl + CIN;
    const int tid = threadIdx.x;
    const int m0 = blockIdx.x * 128;
    const int o0 = blockIdx.y * 64;
    if constexpr (BN) {
        for (int c = tid; c < CIN; c += 256) { scl[c] = scale[c]; shf[c] = shift[c]; }
    }
    f32x4 acc[2][4];
#pragma unroll
    for (int mt = 0; mt < 2; mt++)
#pragma unroll
        for (int ot = 0; ot < 4; ot++) acc[mt][ot] = (f32x4){0.f, 0.f, 0.f, 0.f};
    const int lane = tid & 63, wv = tid >> 6;
    const int l15 = lane & 15, quad = lane >> 4;
    for (int kc = 0; kc < CIN; kc += 32) {
        __syncthreads();
        // stage activations: 128 rows x 32c, straight copy (BN applied in f32, re-round bf16)
#pragma unroll
        for (int i = 0; i < 2; i++) {
            int tt = tid + 256 * i;
            int mr = tt >> 2, cq = (tt & 3) * 8;
            uint4 u = *(const uint4*)(yin + (size_t)(m0 + mr) * CIN + kc + cq);
            if constexpr (BN) {
                float vv[8]; unpack8(u, vv);
#pragma unroll
                for (int e = 0; e < 8; e++)
                    vv[e] = fmaxf(fmaf(vv[e], scl[kc + cq + e], shf[kc + cq + e]), 0.0f);
                u.x = pack2(vv[0], vv[1]); u.y = pack2(vv[2], vv[3]);
                u.z = pack2(vv[4], vv[5]); u.w = pack2(vv[6], vv[7]);
            }
            *(uint4*)&hA[mr * 56 + cq] = u;
        }
        // stage weights hi/lo: 64 rows x 32c
        {
            int orow = tid >> 2, cq = (tid & 3) * 8;
            *(uint4*)&wH[orow * 56 + cq] = *(const uint4*)(whi + (size_t)(o0 + orow) * CIN + kc + cq);
            *(uint4*)&wL[orow * 56 + cq] = *(const uint4*)(wlo + (size_t)(o0 + orow) * CIN + kc + cq);
        }
        __syncthreads();
        bf16x8 a0 = *(bf16x8*)&hA[(wv * 32 + l15) * 56 + quad * 8];
        bf16x8 a1 = *(bf16x8*)&hA[(wv * 32 + 16 + l15) * 56 + quad * 8];
#pragma unroll
        for (int ot = 0; ot < 4; ot++) {
            bf16x8 bh = *(bf16x8*)&wH[(ot * 16 + l15) * 56 + quad * 8];
            bf16x8 bl = *(bf16x8*)&wL[(ot * 16 + l15) * 56 + quad * 8];
            acc[0][ot] = __builtin_amdgcn_mfma_f32_16x16x32_bf16(a0, bh, acc[0][ot], 0, 0, 0);
            acc[0][ot] = __builtin_amdgcn_mfma_f32_16x16x32_bf16(a0, bl, acc[0][ot], 0, 0, 0);
            acc[1][ot] = __builtin_amdgcn_mfma_f32_16x16x32_bf16(a1, bh, acc[1][ot], 0, 0, 0);
            acc[1][ot] = __builtin_amdgcn_mfma_f32_16x16x32_bf16(a1, bl, acc[1][ot], 0, 0, 0);
        }
    }
    // epilogue: LDS transpose -> coalesced NHWC stores
    __syncthreads();
    ushort_t* outT = (ushort_t*)smem;   // [128][72] (rows 144B, 16B aligned)
#pragma unroll
    for (int mt = 0; mt < 2; mt++)
#pragma unroll
        for (int ot = 0; ot < 4; ot++)
#pragma unroll
            for (int r = 0; r < 4; r++)
                outT[(wv * 32 + mt * 16 + quad * 4 + r) * 72 + ot * 16 + l15] = f2bf(acc[mt][ot][r]);
    __syncthreads();
    int row = tid >> 1, half = tid & 1;
#pragma unroll
    for (int g = 0; g < 4; g++) {
        uint4 u = *(uint4*)&outT[row * 72 + half * 32 + g * 8];
        *(uint4*)(yout + (size_t)(m0 + row) * COUT + o0 + half * 32 + g * 8) = u;
    }
}

// ---------------- conv4 fused MFMA: 320m (16 k-windows) x 64o, K=128.
// Epilogue: per-window raw max/min + per-block stats partials (no atomics).
__launch_bounds__(256)
__global__ void conv4_mfma_k(const ushort_t* __restrict__ y3,
                             const ushort_t* __restrict__ whi,
                             const ushort_t* __restrict__ wlo,
                             const float* __restrict__ scale,
                             const float* __restrict__ shift,
                             float* __restrict__ rawmax, float* __restrict__ rawmin,
                             float* __restrict__ sp) {
    __shared__ char smem[53248];
    ushort_t* hA = (ushort_t*)smem;             // [320][56]
    ushort_t* wH = (ushort_t*)(smem + 35840);   // [64][56]
    ushort_t* wL = (ushort_t*)(smem + 43008);   // [64][56]
    float* scl = (float*)(smem + 50176);        // [128]
    float* shf = (float*)(smem + 50688);        // [128]
    float* sw  = (float*)(smem + 51200);        // [4][64][2] per-wave stat partials
    const int tid = threadIdx.x;
    const int m0 = blockIdx.x * 320;
    const int o0 = blockIdx.y * 64;
    for (int c = tid; c < 128; c += 256) { scl[c] = scale[c]; shf[c] = shift[c]; }
    for (int i = tid; i < 512; i += 256) sw[i] = 0.0f;
    f32x4 acc[5][4];
#pragma unroll
    for (int mt = 0; mt < 5; mt++)
#pragma unroll
        for (int ot = 0; ot < 4; ot++) acc[mt][ot] = (f32x4){0.f, 0.f, 0.f, 0.f};
    const int lane = tid & 63, wv = tid >> 6;
    const int l15 = lane & 15, quad = lane >> 4;
    for (int kc = 0; kc < 128; kc += 32) {
        __syncthreads();
#pragma unroll
        for (int i = 0; i < 5; i++) {
            int tt = tid + 256 * i;
            int mr = tt >> 2, cq = (tt & 3) * 8;
            uint4 u = *(const uint4*)(y3 + (size_t)(m0 + mr) * 128 + kc + cq);
            float vv[8]; unpack8(u, vv);
#pragma unroll
            for (int e = 0; e < 8; e++)
                vv[e] = fmaxf(fmaf(vv[e], scl[kc + cq + e], shf[kc + cq + e]), 0.0f);
            u.x = pack2(vv[0], vv[1]); u.y = pack2(vv[2], vv[3]);
            u.z = pack2(vv[4], vv[5]); u.w = pack2(vv[6], vv[7]);
            *(uint4*)&hA[mr * 56 + cq] = u;
        }
        {
            int orow = tid >> 2, cq = (tid & 3) * 8;
            *(uint4*)&wH[orow * 56 + cq] = *(const uint4*)(whi + (size_t)(o0 + orow) * 128 + kc + cq);
            *(uint4*)&wL[orow * 56 + cq] = *(const uint4*)(wlo + (size_t)(o0 + orow) * 128 + kc + cq);
        }
        __syncthreads();
        bf16x8 a[5];
#pragma unroll
        for (int mt = 0; mt < 5; mt++)
            a[mt] = *(bf16x8*)&hA[(wv * 80 + mt * 16 + l15) * 56 + quad * 8];
#pragma unroll
        for (int ot = 0; ot < 4; ot++) {
            bf16x8 bh = *(bf16x8*)&wH[(ot * 16 + l15) * 56 + quad * 8];
            bf16x8 bl = *(bf16x8*)&wL[(ot * 16 + l15) * 56 + quad * 8];
#pragma unroll
            for (int mt = 0; mt < 5; mt++) {
                acc[mt][ot] = __builtin_amdgcn_mfma_f32_16x16x32_bf16(a[mt], bh, acc[mt][ot], 0, 0, 0);
                acc[mt][ot] = __builtin_amdgcn_mfma_f32_16x16x32_bf16(a[mt], bl, acc[mt][ot], 0, 0, 0);
            }
        }
    }
    __syncthreads();
    // epilogue: per wave, 80m x 16o f32 scratch (wave-private), one o-tile at a time
    float* wreg = (float*)(smem + wv * 5440);   // [80][17]
#pragma unroll 1
    for (int ot = 0; ot < 4; ot++) {
#pragma unroll
        for (int mt = 0; mt < 5; mt++)
#pragma unroll
            for (int r = 0; r < 4; r++)
                wreg[(mt * 16 + quad * 4 + r) * 17 + l15] = acc[mt][ot][r];
        __syncthreads();
        {
            int pp = quad;                      // 4 points per wave (80m = 4x20)
            const float* rr = wreg + (pp * 20) * 17 + l15;
            float mx = rr[0], mn = rr[0], sm = 0.0f, ss = 0.0f;
#pragma unroll
            for (int q = 0; q < 20; q++) {
                float v = rr[q * 17];
                mx = fmaxf(mx, v); mn = fminf(mn, v);
                sm += v; ss = fmaf(v, v, ss);
            }
            int pt = blockIdx.x * 16 + wv * 4 + pp;
            int o = o0 + ot * 16 + l15;
            rawmax[(size_t)pt * 256 + o] = mx;
            rawmin[(size_t)pt * 256 + o] = mn;
            sm += __shfl_xor(sm, 16); sm += __shfl_xor(sm, 32);
            ss += __shfl_xor(ss, 16); ss += __shfl_xor(ss, 32);
            if (lane < 16) {
                sw[(wv * 64 + ot * 16 + l15) * 2 + 0] += sm;
                sw[(wv * 64 + ot * 16 + l15) * 2 + 1] += ss;
            }
        }
        __syncthreads();
    }
    if (tid < 64) {
        float sm = 0.0f, ss = 0.0f;
#pragma unroll
        for (int w2 = 0; w2 < 4; w2++) {
            sm += sw[(w2 * 64 + tid) * 2 + 0];
            ss += sw[(w2 * 64 + tid) * 2 + 1];
        }
        size_t bid = (size_t)blockIdx.y * 1024 + blockIdx.x;
        sp[bid * 128 + tid * 2 + 0] = sm;
        sp[bid * 128 + tid * 2 + 1] = ss;
    }
}

// ---------------- reduce conv4 stat partials -> sum/sumsq doubles ----------------
__launch_bounds__(256)
__global__ void stats4red_k(const float* __restrict__ sp, double* __restrict__ sum,
                            double* __restrict__ sumsq) {
    __shared__ double rs[256], rss[256];
    int o = blockIdx.x, tid = threadIdx.x;
    int oy = o >> 6, ol = o & 63;
    double s = 0.0, ss = 0.0;
    for (int mb = tid; mb < 1024; mb += 256) {
        size_t bid = (size_t)oy * 1024 + mb;
        s  += (double)sp[bid * 128 + ol * 2 + 0];
        ss += (double)sp[bid * 128 + ol * 2 + 1];
    }
    rs[tid] = s; rss[tid] = ss;
    __syncthreads();
    for (int st = 128; st; st >>= 1) {
        if (tid < st) { rs[tid] += rs[tid + st]; rss[tid] += rss[tid + st]; }
        __syncthreads();
    }
    if (tid == 0) { sum[o] = rs[0]; sumsq[o] = rss[0]; }
}

// ---------------- per-channel sum/sumsq over NHWC y ----------------
template<int C8>
__launch_bounds__(256)
__global__ void stats_nhwc_k(const ushort_t* __restrict__ y, double* __restrict__ sum,
                             double* __restrict__ sumsq, int rpb) {
    constexpr int C = C8 * 8;
    constexpr int STRIDE = 256 / C8;
    __shared__ float ls[C][2];
    int tid = threadIdx.x;
    for (int i = tid; i < C * 2; i += 256) ((float*)ls)[i] = 0.0f;
    int cg = tid % C8, mr = tid / C8;
    size_t r0 = (size_t)blockIdx.x * rpb;
    float s[8], ss[8];
#pragma unroll
    for (int e = 0; e < 8; e++) { s[e] = 0.0f; ss[e] = 0.0f; }
    for (int r = mr; r < rpb; r += STRIDE) {
        uint4 u = *(const uint4*)(y + (r0 + r) * C + cg * 8);
        float vv[8]; unpack8(u, vv);
#pragma unroll
        for (int e = 0; e < 8; e++) { s[e] += vv[e]; ss[e] = fmaf(vv[e], vv[e], ss[e]); }
    }
    __syncthreads();
#pragma unroll
    for (int e = 0; e < 8; e++) {
        atomicAdd(&ls[cg * 8 + e][0], s[e]);
        atomicAdd(&ls[cg * 8 + e][1], ss[e]);
    }
    __syncthreads();
    // FIX (round 4 bug): C can exceed blockDim (C=512, 256 threads) — use strided loop,
    // not `if (tid < C)`, else channels >= 256 never accumulate -> BN scale = 1/sqrt(eps).
    for (int c = tid; c < C; c += 256) {
        atomicAdd(&sum[c], (double)ls[c][0]);
        atomicAdd(&sumsq[c], (double)ls[c][1]);
    }
}

// ---------------- finalize BN ----------------
__global__ void fin_k(const double* __restrict__ sum, const double* __restrict__ sumsq,
                      const float* __restrict__ g, const float* __restrict__ bb,
                      float* __restrict__ scale, float* __restrict__ shift, int C, double invcnt) {
    int c = blockIdx.x * blockDim.x + threadIdx.x;
    if (c < C) {
        double m = sum[c] * invcnt;
        double v = sumsq[c] * invcnt - m * m;
        if (v < 0.0) v = 0.0;
        float sc = g[c] / sqrtf((float)v + 1e-5f);
        scale[c] = sc;
        shift[c] = bb[c] - (float)m * sc;
    }
}

// ---------------- maxpool over k (BN+ReLU) NHWC -> xcat (layers 1-3) ----------------
template<int C8>
__launch_bounds__(256)
__global__ void maxpool_nhwc_k(const ushort_t* __restrict__ y, const float* __restrict__ scale,
                               const float* __restrict__ shift, ushort_t* __restrict__ xcat,
                               int coff) {
    constexpr int C = C8 * 8;
    constexpr int PB = 256 / C8;
    int tid = threadIdx.x;
    int cg = tid % C8, pl = tid / C8;
    int p = blockIdx.x * PB + pl;
    float sc[8], sh[8];
    *(float4*)&sc[0] = *(const float4*)(scale + cg * 8);
    *(float4*)&sc[4] = *(const float4*)(scale + cg * 8 + 4);
    *(float4*)&sh[0] = *(const float4*)(shift + cg * 8);
    *(float4*)&sh[4] = *(const float4*)(shift + cg * 8 + 4);
    float mx[8];
#pragma unroll
    for (int e = 0; e < 8; e++) mx[e] = 0.0f;   // relu floor
    size_t base = (size_t)p * KNN * C + cg * 8;
#pragma unroll
    for (int q = 0; q < KNN; q++) {
        uint4 u = *(const uint4*)(y + base + (size_t)q * C);
        float vv[8]; unpack8(u, vv);
#pragma unroll
        for (int e = 0; e < 8; e++) mx[e] = fmaxf(mx[e], fmaf(vv[e], sc[e], sh[e]));
    }
    uint4 u;
    u.x = pack2(mx[0], mx[1]); u.y = pack2(mx[2], mx[3]);
    u.z = pack2(mx[4], mx[5]); u.w = pack2(mx[6], mx[7]);
    *(uint4*)(xcat + (size_t)p * 512 + coff + cg * 8) = u;
}

// ---------------- pool4 finalize: BN of raw max/min + ReLU -> xcat[.][256..512) ----------------
__launch_bounds__(256)
__global__ void pool4_k(const float* __restrict__ rawmax, const float* __restrict__ rawmin,
                        const float* __restrict__ scale, const float* __restrict__ shift,
                        ushort_t* __restrict__ xcat) {
    int gid = blockIdx.x * 256 + threadIdx.x;   // 524288
    int p = gid >> 5, og = gid & 31;
    float sc[8], sh[8], mxv[8], mnv[8];
    *(float4*)&sc[0]  = *(const float4*)(scale + og * 8);
    *(float4*)&sc[4]  = *(const float4*)(scale + og * 8 + 4);
    *(float4*)&sh[0]  = *(const float4*)(shift + og * 8);
    *(float4*)&sh[4]  = *(const float4*)(shift + og * 8 + 4);
    *(float4*)&mxv[0] = *(const float4*)(rawmax + (size_t)p * 256 + og * 8);
    *(float4*)&mxv[4] = *(const float4*)(rawmax + (size_t)p * 256 + og * 8 + 4);
    *(float4*)&mnv[0] = *(const float4*)(rawmin + (size_t)p * 256 + og * 8);
    *(float4*)&mnv[4] = *(const float4*)(rawmin + (size_t)p * 256 + og * 8 + 4);
    float v[8];
#pragma unroll
    for (int e = 0; e < 8; e++) {
        float raw = (sc[e] >= 0.0f) ? mxv[e] : mnv[e];
        v[e] = fmaxf(fmaf(raw, sc[e], sh[e]), 0.0f);
    }
    uint4 u;
    u.x = pack2(v[0], v[1]); u.y = pack2(v[2], v[3]);
    u.z = pack2(v[4], v[5]); u.w = pack2(v[6], v[7]);
    *(uint4*)(xcat + (size_t)p * 512 + 256 + og * 8) = u;
}

// ---------------- output: BN5+ReLU + transpose NHWC -> [b][c][n] fp32 ----------------
__launch_bounds__(256)
__global__ void out_k(const ushort_t* __restrict__ y5, const float* __restrict__ scale,
                      const float* __restrict__ shift, float* __restrict__ out) {
    __shared__ float tr[64 * 65];
    int tid = threadIdx.x;
    int n0 = blockIdx.x * 64, c0 = blockIdx.y * 64, b = blockIdx.z;
    int nl = tid >> 2, cq = (tid & 3) * 16;
    const ushort_t* src = y5 + (size_t)(b * 2048 + n0 + nl) * 512 + c0 + cq;
#pragma unroll
    for (int h = 0; h < 2; h++) {
        uint4 u = *(const uint4*)(src + h * 8);
        float vv[8]; unpack8(u, vv);
#pragma unroll
        for (int e = 0; e < 8; e++) {
            int c = cq + h * 8 + e;
            tr[c * 65 + nl] = fmaxf(fmaf(vv[e], scale[c0 + c], shift[c0 + c]), 0.0f);
        }
    }
    __syncthreads();
    int cl = tid >> 2, ng = (tid & 3) * 16;
#pragma unroll
    for (int g = 0; g < 4; g++) {
        float4 v = *(float4*)&tr[cl * 65 + ng + g * 4];
        *(float4*)(out + ((size_t)b * 512 + c0 + cl) * 2048 + n0 + ng + g * 4) = v;
    }
}

// ---------------- host ----------------
extern "C" void kernel_launch(void* const* d_in, const int* in_sizes, int n_in,
                              void* d_out, int out_size, void* d_ws, size_t ws_size,
                              hipStream_t stream) {
    (void)in_sizes; (void)n_in; (void)out_size;
    if (ws_size < WS_NEEDED) return;
    const float* x  = (const float*)d_in[0];
    const float* w1 = (const float*)d_in[1];
    const float* g1 = (const float*)d_in[2];
    const float* b1 = (const float*)d_in[3];
    const float* w2 = (const float*)d_in[4];
    const float* g2 = (const float*)d_in[5];
    const float* b2 = (const float*)d_in[6];
    const float* w3 = (const float*)d_in[7];
    const float* g3 = (const float*)d_in[8];
    const float* b3 = (const float*)d_in[9];
    const float* w4 = (const float*)d_in[10];
    const float* g4 = (const float*)d_in[11];
    const float* b4 = (const float*)d_in[12];
    const float* w5 = (const float*)d_in[13];
    const float* g5 = (const float*)d_in[14];
    const float* b5 = (const float*)d_in[15];

    char* ws = (char*)d_ws;
    float* xt  = (float*)(ws + OFF_XT);
    float* xx  = (float*)(ws + OFF_XX);
    int*   idx = (int*)(ws + OFF_IDX);
    ushort_t* wh2 = (ushort_t*)(ws + OFF_WH2); ushort_t* wl2 = (ushort_t*)(ws + OFF_WL2);
    ushort_t* wh3 = (ushort_t*)(ws + OFF_WH3); ushort_t* wl3 = (ushort_t*)(ws + OFF_WL3);
    ushort_t* wh4 = (ushort_t*)(ws + OFF_WH4); ushort_t* wl4 = (ushort_t*)(ws + OFF_WL4);
    ushort_t* wh5 = (ushort_t*)(ws + OFF_WH5); ushort_t* wl5 = (ushort_t*)(ws + OFF_WL5);
    ushort_t* y1 = (ushort_t*)(ws + OFF_REG0);
    ushort_t* y2 = (ushort_t*)(ws + OFF_REG1);
    ushort_t* y3 = (ushort_t*)(ws + OFF_REG0);
    float* rawmax = (float*)(ws + OFF_REG1);
    float* rawmin = (float*)(ws + OFF_REG1 + 16777216UL);
    float* sp4    = (float*)(ws + OFF_REG1 + 33554432UL);  // 2 MB partials
    ushort_t* y5 = (ushort_t*)(ws + OFF_REG0);
    ushort_t* xcat = (ushort_t*)(ws + OFF_XCAT);

    double* sum[5]; double* sumsq[5]; float* scl[5]; float* shf[5];
    for (int l = 0; l < 5; l++) {
        sum[l]   = (double*)(ws + OFF_STATS + (size_t)l * 8192);
        sumsq[l] = sum[l] + 512;
        scl[l]   = (float*)(ws + OFF_SS + (size_t)l * 4096);
        shf[l]   = scl[l] + 512;
    }

    hipMemsetAsync(ws + OFF_STATS, 0, 40960, stream);
    prep_k<<<64, 256, 0, stream>>>(x, xt, xx);
    wsplit_k<<<16,   256, 0, stream>>>(w2, wh2, wl2, 4096);
    wsplit_k<<<32,   256, 0, stream>>>(w3, wh3, wl3, 8192);
    wsplit_k<<<128,  256, 0, stream>>>(w4, wh4, wl4, 32768);
    wsplit_k<<<1024, 256, 0, stream>>>(w5, wh5, wl5, 262144);
    knn_k<<<4096, 256, 0, stream>>>(xt, xx, idx);

    // layer 1
    conv1_k<<<1280, 256, 0, stream>>>(xt, idx, w1, y1);
    stats_nhwc_k<8><<<160, 256, 0, stream>>>(y1, sum[0], sumsq[0], 2048);
    fin_k<<<1, 512, 0, stream>>>(sum[0], sumsq[0], g1, b1, scl[0], shf[0], 64, 1.0 / 327680.0);
    maxpool_nhwc_k<8><<<512, 256, 0, stream>>>(y1, scl[0], shf[0], xcat, 0);

    // layer 2: 64 -> 64
    conv_mfma_k<64, 64, true><<<dim3(2560, 1), 256, 0, stream>>>(y1, wh2, wl2, scl[0], shf[0], y2);
    stats_nhwc_k<8><<<160, 256, 0, stream>>>(y2, sum[1], sumsq[1], 2048);
    fin_k<<<1, 512, 0, stream>>>(sum[1], sumsq[1], g2, b2, scl[1], shf[1], 64, 1.0 / 327680.0);
    maxpool_nhwc_k<8><<<512, 256, 0, stream>>>(y2, scl[1], shf[1], xcat, 64);

    // layer 3: 64 -> 128
    conv_mfma_k<64, 128, true><<<dim3(2560, 2), 256, 0, stream>>>(y2, wh3, wl3, scl[1], shf[1], y3);
    stats_nhwc_k<16><<<320, 256, 0, stream>>>(y3, sum[2], sumsq[2], 1024);
    fin_k<<<1, 512, 0, stream>>>(sum[2], sumsq[2], g3, b3, scl[2], shf[2], 128, 1.0 / 327680.0);
    maxpool_nhwc_k<16><<<1024, 256, 0, stream>>>(y3, scl[2], shf[2], xcat, 128);

    // layer 4: 128 -> 256 fused (no y4), partial stats
    conv4_mfma_k<<<dim3(1024, 4), 256, 0, stream>>>(y3, wh4, wl4, scl[2], shf[2],
                                                    rawmax, rawmin, sp4);
    stats4red_k<<<256, 256, 0, stream>>>(sp4, sum[3], sumsq[3]);
    fin_k<<<1, 512, 0, stream>>>(sum[3], sumsq[3], g4, b4, scl[3], shf[3], 256, 1.0 / 327680.0);
    pool4_k<<<2048, 256, 0, stream>>>(rawmax, rawmin, scl[3], shf[3], xcat);

    // layer 5: 512 -> 512 (input already activated)
    conv_mfma_k<512, 512, false><<<dim3(128, 8), 256, 0, stream>>>(xcat, wh5, wl5,
                                                                   nullptr, nullptr, y5);
    stats_nhwc_k<64><<<128, 256, 0, stream>>>(y5, sum[4], sumsq[4], 128);
    fin_k<<<1, 512, 0, stream>>>(sum[4], sumsq[4], g5, b5, scl[4], shf[4], 512, 1.0 / 16384.0);
    out_k<<<dim3(32, 8, 8), 256, 0, stream>>>(y5, scl[4], shf[4], (float*)d_out);
}